// Round 1
// baseline (9708.806 us; speedup 1.0000x reference)
//
#include <hip/hip_runtime.h>

#define HIDDEN 128
#define NRBF 50
#define CUTOFF_F 5.0f
#define PI_OVER_CUTOFF 0.6283185307179586f

// ---------------------------------------------------------------------------
// Edge kernel: one edge per lane.
//   W[h] = (edge_attr[e,:] . dp_w[h,:] + dp_b[h]) * C(r)
//   msg[h] = W[h] * emb[z[dst]][h];  atomicAdd(agg[src][h], msg[h])
// edge_attr row lives in 50 VGPRs; dp_w/dp_b reads are wave-uniform -> s_load.
// ---------------------------------------------------------------------------
__global__ __launch_bounds__(256) void edge_kernel(
    const int* __restrict__ z, const int* __restrict__ ei,
    const float* __restrict__ ew, const float* __restrict__ ea,
    const float* __restrict__ emb, const float* __restrict__ dpw,
    const float* __restrict__ dpb, float* __restrict__ agg, int E)
{
    int e = blockIdx.x * 256 + threadIdx.x;
    if (e >= E) return;
    float r = ew[e];
    if (!(r < CUTOFF_F)) return;                   // C == 0 -> no contribution
    float C = 0.5f * (cosf(r * PI_OVER_CUTOFF) + 1.0f);
    int src = ei[e];
    int dst = ei[E + e];
    int zt  = z[dst];

    float av[NRBF];
#pragma unroll
    for (int k = 0; k < NRBF; ++k) av[k] = ea[(size_t)e * NRBF + k];

    const float* er = emb + (size_t)zt * HIDDEN;
    float*       ar = agg + (size_t)src * HIDDEN;

#pragma unroll 2
    for (int h = 0; h < HIDDEN; ++h) {
        const float* wrow = dpw + h * NRBF;        // uniform address -> s_load
        float s0 = 0.f, s1 = 0.f;
#pragma unroll
        for (int k = 0; k < NRBF; k += 2) {
            s0 = fmaf(av[k],     wrow[k],     s0);
            s1 = fmaf(av[k + 1], wrow[k + 1], s1);
        }
        float w = (dpb[h] + s0 + s1) * C;
        unsafeAtomicAdd(&ar[h], w * er[h]);        // HW global_atomic_add_f32
    }
}

// ---------------------------------------------------------------------------
// Combine kernel: out[n] = [node_feat[n] | agg[n]] @ comb_w.T + comb_b
// One row per lane. agg lives in d_out (in-place): the full agg row is
// preloaded into 128 VGPRs before any store, so overwriting is safe.
// comb_w/comb_b reads are wave-uniform -> s_load (1 v_fmac per MAC).
// ---------------------------------------------------------------------------
__global__ __launch_bounds__(64) void combine_kernel(
    const float* __restrict__ nf, const float* __restrict__ cw,
    const float* __restrict__ cb, float* __restrict__ out, int N)
{
    int n = blockIdx.x * 64 + threadIdx.x;
    if (n >= N) return;

    float xa[HIDDEN];                              // agg row in registers
    const float4* ap = (const float4*)(out + (size_t)n * HIDDEN);
#pragma unroll
    for (int q = 0; q < HIDDEN / 4; ++q) ((float4*)xa)[q] = ap[q];

    const float4* xp = (const float4*)(nf + (size_t)n * HIDDEN);
    float4*       op = (float4*)(out + (size_t)n * HIDDEN);

    for (int jc = 0; jc < 8; ++jc) {               // 16 output cols per chunk
        float acc[16];
#pragma unroll
        for (int jj = 0; jj < 16; ++jj) acc[jj] = cb[jc * 16 + jj];

        // node_feat half (k = 0..127), streamed from global per chunk
        for (int kc = 0; kc < 4; ++kc) {
            float xk[32];
#pragma unroll
            for (int q = 0; q < 8; ++q) ((float4*)xk)[q] = xp[kc * 8 + q];
#pragma unroll
            for (int kk = 0; kk < 32; ++kk)
#pragma unroll
                for (int jj = 0; jj < 16; ++jj)
                    acc[jj] = fmaf(xk[kk],
                                   cw[(jc * 16 + jj) * 256 + kc * 32 + kk],
                                   acc[jj]);
        }
        // agg half (k = 128..255), from registers (static indices only)
#pragma unroll
        for (int kc = 0; kc < 4; ++kc)
#pragma unroll
            for (int kk = 0; kk < 32; ++kk)
#pragma unroll
                for (int jj = 0; jj < 16; ++jj)
                    acc[jj] = fmaf(xa[kc * 32 + kk],
                                   cw[(jc * 16 + jj) * 256 + 128 + kc * 32 + kk],
                                   acc[jj]);
#pragma unroll
        for (int q = 0; q < 4; ++q)
            op[jc * 4 + q] = make_float4(acc[q * 4], acc[q * 4 + 1],
                                         acc[q * 4 + 2], acc[q * 4 + 3]);
    }
}

extern "C" void kernel_launch(void* const* d_in, const int* in_sizes, int n_in,
                              void* d_out, int out_size, void* d_ws, size_t ws_size,
                              hipStream_t stream)
{
    const int*   z   = (const int*)  d_in[0];
    const float* nf  = (const float*)d_in[1];
    const int*   ei  = (const int*)  d_in[2];
    const float* ew  = (const float*)d_in[3];
    const float* ea  = (const float*)d_in[4];
    const float* emb = (const float*)d_in[5];
    const float* dpw = (const float*)d_in[6];
    const float* dpb = (const float*)d_in[7];
    const float* cw  = (const float*)d_in[8];
    const float* cb  = (const float*)d_in[9];
    float* out = (float*)d_out;

    int N = in_sizes[0];       // 100000 nodes
    int E = in_sizes[3];       // 1600000 edges

    // agg accumulator lives in d_out; zero it first
    hipMemsetAsync(out, 0, (size_t)N * HIDDEN * sizeof(float), stream);

    edge_kernel<<<(E + 255) / 256, 256, 0, stream>>>(z, ei, ew, ea, emb, dpw,
                                                     dpb, out, E);
    combine_kernel<<<(N + 63) / 64, 64, 0, stream>>>(nf, cw, cb, out, N);
}

// Round 2
// 739.539 us; speedup vs baseline: 13.1282x; 13.1282x over previous
//
#include <hip/hip_runtime.h>

#define HIDDEN 128
#define NRBF 50
#define CUTOFF_F 5.0f
#define PI_OVER_CUTOFF 0.6283185307179586f

// ======================= CSR build =======================

__global__ __launch_bounds__(256) void hist_kernel(
    const int* __restrict__ ei, const float* __restrict__ ew,
    int* __restrict__ cnt, int E)
{
    int e = blockIdx.x * 256 + threadIdx.x;
    if (e >= E) return;
    float r = ew[e];
    if (r < CUTOFF_F) atomicAdd(&cnt[ei[e]], 1);
}

// block scans 1024 elements (256 threads x 4)
__global__ __launch_bounds__(256) void scan1_kernel(
    const int* __restrict__ cnt, int* __restrict__ rowptr,
    int* __restrict__ bsum, int N)
{
    __shared__ int sh[256];
    int t = threadIdx.x, b = blockIdx.x;
    int base = b * 1024 + t * 4;
    int v[4];
#pragma unroll
    for (int j = 0; j < 4; ++j) v[j] = (base + j < N) ? cnt[base + j] : 0;
    int s = v[0] + v[1] + v[2] + v[3];
    sh[t] = s;
    __syncthreads();
    for (int off = 1; off < 256; off <<= 1) {
        int x = (t >= off) ? sh[t - off] : 0;
        __syncthreads();
        sh[t] += x;
        __syncthreads();
    }
    int run = sh[t] - s;                    // exclusive prefix of this thread
#pragma unroll
    for (int j = 0; j < 4; ++j) {
        if (base + j < N) rowptr[base + j] = run;
        run += v[j];
    }
    if (t == 255) bsum[b] = sh[255];
}

__global__ __launch_bounds__(256) void scan2_kernel(
    int* __restrict__ bsum, int* __restrict__ rowptr, int nb, int N)
{
    __shared__ int sh[256];
    int t = threadIdx.x;
    int v = (t < nb) ? bsum[t] : 0;
    sh[t] = v;
    __syncthreads();
    for (int off = 1; off < 256; off <<= 1) {
        int x = (t >= off) ? sh[t - off] : 0;
        __syncthreads();
        sh[t] += x;
        __syncthreads();
    }
    if (t < nb) bsum[t] = sh[t] - v;        // exclusive block offsets
    if (t == 255) rowptr[N] = sh[255];      // total live edges
}

__global__ __launch_bounds__(256) void scan3_kernel(
    int* __restrict__ rowptr, int* __restrict__ woff,
    const int* __restrict__ bsum, int N)
{
    int t = threadIdx.x, b = blockIdx.x;
    int base = b * 1024 + t * 4;
    int off = bsum[b];
#pragma unroll
    for (int j = 0; j < 4; ++j) {
        int i = base + j;
        if (i < N) {
            int r = rowptr[i] + off;
            rowptr[i] = r;
            woff[i] = r;
        }
    }
}

__global__ __launch_bounds__(256) void scatter_kernel(
    const int* __restrict__ z, const int* __restrict__ ei,
    const float* __restrict__ ew, int* __restrict__ woff,
    int* __restrict__ eidA, int* __restrict__ zztA, float* __restrict__ cCA,
    int E)
{
    int e = blockIdx.x * 256 + threadIdx.x;
    if (e >= E) return;
    float r = ew[e];
    if (!(r < CUTOFF_F)) return;
    float C = 0.5f * (cosf(r * PI_OVER_CUTOFF) + 1.0f);
    int src = ei[e];
    int dst = ei[E + e];
    int zt  = z[dst];
    int p = atomicAdd(&woff[src], 1);
    eidA[p] = e;
    zztA[p] = zt;
    cCA[p]  = C;
}

// ======================= Gather (agg) =======================
// One wave per node (grid-strided). Lane owns channels h0=2*lane, h0+1 with
// its dp_w rows (100 floats) preloaded in VGPRs. Per edge: the 50 RBF values
// are wave-uniform -> scalar loads; 100 v_fma per wave per edge.
__global__ __launch_bounds__(256) void gather_kernel(
    const int* __restrict__ rowptr, const int* __restrict__ eidA,
    const int* __restrict__ zztA, const float* __restrict__ cCA,
    const float* __restrict__ ea, const float* __restrict__ emb,
    const float* __restrict__ dpw, const float* __restrict__ dpb,
    float* __restrict__ agg, int N)
{
    int lane = threadIdx.x & 63;
    int wid0 = (blockIdx.x * blockDim.x + threadIdx.x) >> 6;
    int nw   = (gridDim.x * blockDim.x) >> 6;

    float4 wreg[25];                               // rows 2*lane, 2*lane+1
    const float4* wp = (const float4*)(dpw + lane * 100);
#pragma unroll
    for (int q = 0; q < 25; ++q) wreg[q] = wp[q];
    const float* w0 = (const float*)wreg;          // [0..49]=h0, [50..99]=h0+1
    float2 db = *(const float2*)(dpb + 2 * lane);

    for (int n0 = wid0; n0 < N; n0 += nw) {
        int n = __builtin_amdgcn_readfirstlane(n0);
        int start = rowptr[n], end = rowptr[n + 1];
        float a0 = 0.f, a1 = 0.f;
        for (int i = start; i < end; ++i) {
            int e   = eidA[i];
            int zt  = zztA[i];
            float Cf = cCA[i];
            const float* ar = ea + (size_t)e * NRBF;   // uniform -> s_load
            float s0 = 0.f, s1 = 0.f;
#pragma unroll
            for (int k = 0; k < NRBF; ++k) {
                float a = ar[k];
                s0 = fmaf(a, w0[k],      s0);
                s1 = fmaf(a, w0[50 + k], s1);
            }
            float2 ev = *(const float2*)(emb + (size_t)zt * HIDDEN + 2 * lane);
            float W0 = (s0 + db.x) * Cf;
            float W1 = (s1 + db.y) * Cf;
            a0 = fmaf(W0, ev.x, a0);
            a1 = fmaf(W1, ev.y, a1);
        }
        *(float2*)(agg + (size_t)n * HIDDEN + 2 * lane) = make_float2(a0, a1);
    }
}

// ======================= Fallback edge kernel (atomics) =======================
__global__ __launch_bounds__(256) void edge_kernel(
    const int* __restrict__ z, const int* __restrict__ ei,
    const float* __restrict__ ew, const float* __restrict__ ea,
    const float* __restrict__ emb, const float* __restrict__ dpw,
    const float* __restrict__ dpb, float* __restrict__ agg, int E)
{
    int e = blockIdx.x * 256 + threadIdx.x;
    if (e >= E) return;
    float r = ew[e];
    if (!(r < CUTOFF_F)) return;
    float C = 0.5f * (cosf(r * PI_OVER_CUTOFF) + 1.0f);
    int src = ei[e];
    int dst = ei[E + e];
    int zt  = z[dst];
    float av[NRBF];
#pragma unroll
    for (int k = 0; k < NRBF; ++k) av[k] = ea[(size_t)e * NRBF + k];
    const float* er = emb + (size_t)zt * HIDDEN;
    float*       ar = agg + (size_t)src * HIDDEN;
#pragma unroll 2
    for (int h = 0; h < HIDDEN; ++h) {
        const float* wrow = dpw + h * NRBF;
        float s0 = 0.f, s1 = 0.f;
#pragma unroll
        for (int k = 0; k < NRBF; k += 2) {
            s0 = fmaf(av[k],     wrow[k],     s0);
            s1 = fmaf(av[k + 1], wrow[k + 1], s1);
        }
        float w = (dpb[h] + s0 + s1) * C;
        unsafeAtomicAdd(&ar[h], w * er[h]);
    }
}

// ======================= Combine: tiled fp32 GEMM =======================
// out[n] = [nf[n] | agg[n]] @ cw.T + cb, agg lives in `out` (in place).
// Block: 64 rows x 128 cols, K=256 in 8 chunks of 32, k-major LDS tiles.
__global__ __launch_bounds__(256) void combine_tiled(
    const float* __restrict__ nf, const float* __restrict__ cw,
    const float* __restrict__ cb, float* out, int N)
{
    __shared__ float As[32][68];    // [kk][m], padded
    __shared__ float Bs[32][132];   // [kk][j], padded
    int tid  = threadIdx.x;
    int row0 = blockIdx.x * 64;
    int mt = (tid >> 4) << 2;       // 0,4,...,60
    int nt = (tid & 15) << 3;       // 0,8,...,120

    float acc[4][8];
    {
        float4 c0 = *(const float4*)(cb + nt);
        float4 c1 = *(const float4*)(cb + nt + 4);
#pragma unroll
        for (int mi = 0; mi < 4; ++mi) {
            acc[mi][0] = c0.x; acc[mi][1] = c0.y; acc[mi][2] = c0.z; acc[mi][3] = c0.w;
            acc[mi][4] = c1.x; acc[mi][5] = c1.y; acc[mi][6] = c1.z; acc[mi][7] = c1.w;
        }
    }

    for (int kc = 0; kc < 8; ++kc) {
        const float* src = (kc < 4) ? nf : out;     // second half reads agg
        int kbase = (kc & 3) * 32;
        // stage A: 64 rows x 32 k -> As[kk][m]
#pragma unroll
        for (int f = tid; f < 512; f += 256) {
            int r = f >> 3, kq = (f & 7) * 4;
            int row = row0 + r;
            float4 v = make_float4(0.f, 0.f, 0.f, 0.f);
            if (row < N) v = *(const float4*)(src + (size_t)row * HIDDEN + kbase + kq);
            As[kq + 0][r] = v.x; As[kq + 1][r] = v.y;
            As[kq + 2][r] = v.z; As[kq + 3][r] = v.w;
        }
        // stage B: 128 cols x 32 k -> Bs[kk][j]
#pragma unroll
        for (int f = tid; f < 1024; f += 256) {
            int j = f >> 3, kq = (f & 7) * 4;
            float4 v = *(const float4*)(cw + (size_t)j * 256 + kc * 32 + kq);
            Bs[kq + 0][j] = v.x; Bs[kq + 1][j] = v.y;
            Bs[kq + 2][j] = v.z; Bs[kq + 3][j] = v.w;
        }
        __syncthreads();
#pragma unroll
        for (int kk = 0; kk < 32; ++kk) {
            float4 a  = *(const float4*)&As[kk][mt];
            float4 b0 = *(const float4*)&Bs[kk][nt];
            float4 b1 = *(const float4*)&Bs[kk][nt + 4];
            const float am[4] = {a.x, a.y, a.z, a.w};
            const float bn[8] = {b0.x, b0.y, b0.z, b0.w, b1.x, b1.y, b1.z, b1.w};
#pragma unroll
            for (int mi = 0; mi < 4; ++mi)
#pragma unroll
                for (int nj = 0; nj < 8; ++nj)
                    acc[mi][nj] = fmaf(am[mi], bn[nj], acc[mi][nj]);
        }
        __syncthreads();
    }
    // store
#pragma unroll
    for (int mi = 0; mi < 4; ++mi) {
        int row = row0 + mt + mi;
        if (row < N) {
            float4* op = (float4*)(out + (size_t)row * HIDDEN + nt);
            op[0] = make_float4(acc[mi][0], acc[mi][1], acc[mi][2], acc[mi][3]);
            op[1] = make_float4(acc[mi][4], acc[mi][5], acc[mi][6], acc[mi][7]);
        }
    }
}

// ======================= launch =======================

extern "C" void kernel_launch(void* const* d_in, const int* in_sizes, int n_in,
                              void* d_out, int out_size, void* d_ws, size_t ws_size,
                              hipStream_t stream)
{
    const int*   z   = (const int*)  d_in[0];
    const float* nf  = (const float*)d_in[1];
    const int*   ei  = (const int*)  d_in[2];
    const float* ew  = (const float*)d_in[3];
    const float* ea  = (const float*)d_in[4];
    const float* emb = (const float*)d_in[5];
    const float* dpw = (const float*)d_in[6];
    const float* dpb = (const float*)d_in[7];
    const float* cw  = (const float*)d_in[8];
    const float* cb  = (const float*)d_in[9];
    float* out = (float*)d_out;

    int N = in_sizes[0];
    int E = in_sizes[3];

    size_t need = ((size_t)2 * N + 1 + 1024 + (size_t)3 * E) * 4;

    if (ws_size >= need) {
        int* rowptr = (int*)d_ws;                  // N+1
        int* woff   = rowptr + (N + 1);            // N
        int* bsum   = woff + N;                    // 1024
        int* eidA   = bsum + 1024;                 // E
        int* zztA   = eidA + E;                    // E
        float* cCA  = (float*)(zztA + E);          // E

        int nb1 = (N + 1023) / 1024;

        hipMemsetAsync(woff, 0, (size_t)N * 4, stream);
        hist_kernel<<<(E + 255) / 256, 256, 0, stream>>>(ei, ew, woff, E);
        scan1_kernel<<<nb1, 256, 0, stream>>>(woff, rowptr, bsum, N);
        scan2_kernel<<<1, 256, 0, stream>>>(bsum, rowptr, nb1, N);
        scan3_kernel<<<nb1, 256, 0, stream>>>(rowptr, woff, bsum, N);
        scatter_kernel<<<(E + 255) / 256, 256, 0, stream>>>(z, ei, ew, woff,
                                                            eidA, zztA, cCA, E);
        gather_kernel<<<3072, 256, 0, stream>>>(rowptr, eidA, zztA, cCA,
                                                ea, emb, dpw, dpb, out, N);
    } else {
        // fallback: atomic scatter path
        hipMemsetAsync(out, 0, (size_t)N * HIDDEN * sizeof(float), stream);
        edge_kernel<<<(E + 255) / 256, 256, 0, stream>>>(z, ei, ew, ea, emb,
                                                         dpw, dpb, out, E);
    }

    combine_tiled<<<(N + 63) / 64, 256, 0, stream>>>(nf, cw, cb, out, N);
}

// Round 4
// 497.920 us; speedup vs baseline: 19.4987x; 1.4853x over previous
//
#include <hip/hip_runtime.h>

#define HIDDEN 128
#define NRBF 50
#define CUTOFF_F 5.0f
#define PI_OVER_CUTOFF 0.6283185307179586f

typedef __attribute__((ext_vector_type(2))) _Float16 hf2;

#if defined(__has_builtin)
#if __has_builtin(__builtin_amdgcn_fdot2)
#define HAS_FDOT2 1
#endif
#endif

static __device__ __forceinline__ hf2 pack2(float x, float y) {
    return __builtin_bit_cast(hf2, __builtin_amdgcn_cvt_pkrtz(x, y));
}

static __device__ __forceinline__ float fdot2f(hf2 a, hf2 b, float c) {
#ifdef HAS_FDOT2
    return __builtin_amdgcn_fdot2(a, b, c, false);
#else
    return fmaf((float)a[0], (float)b[0], fmaf((float)a[1], (float)b[1], c));
#endif
}

// ======================= CSR build =======================

__global__ __launch_bounds__(256) void hist_kernel(
    const int* __restrict__ ei, const float* __restrict__ ew,
    int* __restrict__ cnt, int E)
{
    int e = blockIdx.x * 256 + threadIdx.x;
    if (e >= E) return;
    float r = ew[e];
    if (r < CUTOFF_F) atomicAdd(&cnt[ei[e]], 1);
}

__global__ __launch_bounds__(256) void scan1_kernel(
    const int* __restrict__ cnt, int* __restrict__ rowptr,
    int* __restrict__ bsum, int N)
{
    __shared__ int sh[256];
    int t = threadIdx.x, b = blockIdx.x;
    int base = b * 1024 + t * 4;
    int v[4];
#pragma unroll
    for (int j = 0; j < 4; ++j) v[j] = (base + j < N) ? cnt[base + j] : 0;
    int s = v[0] + v[1] + v[2] + v[3];
    sh[t] = s;
    __syncthreads();
    for (int off = 1; off < 256; off <<= 1) {
        int x = (t >= off) ? sh[t - off] : 0;
        __syncthreads();
        sh[t] += x;
        __syncthreads();
    }
    int run = sh[t] - s;
#pragma unroll
    for (int j = 0; j < 4; ++j) {
        if (base + j < N) rowptr[base + j] = run;
        run += v[j];
    }
    if (t == 255) bsum[b] = sh[255];
}

__global__ __launch_bounds__(256) void scan2_kernel(
    int* __restrict__ bsum, int* __restrict__ rowptr, int nb, int N)
{
    __shared__ int sh[256];
    int t = threadIdx.x;
    int v = (t < nb) ? bsum[t] : 0;
    sh[t] = v;
    __syncthreads();
    for (int off = 1; off < 256; off <<= 1) {
        int x = (t >= off) ? sh[t - off] : 0;
        __syncthreads();
        sh[t] += x;
        __syncthreads();
    }
    if (t < nb) bsum[t] = sh[t] - v;
    if (t == 255) rowptr[N] = sh[255];
}

__global__ __launch_bounds__(256) void scan3_kernel(
    int* __restrict__ rowptr, int* __restrict__ woff,
    const int* __restrict__ bsum, int N)
{
    int t = threadIdx.x, b = blockIdx.x;
    int base = b * 1024 + t * 4;
    int off = bsum[b];
#pragma unroll
    for (int j = 0; j < 4; ++j) {
        int i = base + j;
        if (i < N) {
            int r = rowptr[i] + off;
            rowptr[i] = r;
            woff[i] = r;
        }
    }
}

// scatter live edges into CSR order; pack src|zt<<20 (N<2^20, zt<95)
__global__ __launch_bounds__(256) void scatter_kernel(
    const int* __restrict__ z, const int* __restrict__ ei,
    const float* __restrict__ ew, int* __restrict__ woff,
    int* __restrict__ srczt, float* __restrict__ cCA, int* __restrict__ eidA,
    int E)
{
    int e = blockIdx.x * 256 + threadIdx.x;
    if (e >= E) return;
    float r = ew[e];
    if (!(r < CUTOFF_F)) return;
    float C = 0.5f * (cosf(r * PI_OVER_CUTOFF) + 1.0f);
    int src = ei[e];
    int dst = ei[E + e];
    int zt  = z[dst];
    int p = atomicAdd(&woff[src], 1);
    srczt[p] = src | (zt << 20);
    cCA[p]   = C;
    eidA[p]  = e;
}

// ======================= Streaming gather =======================
// Wave owns a contiguous CSR chunk. Lane owns h = 2*lane, 2*lane+1 with f16
// dp_w pairs in VGPRs. Per edge: lanes 0-24 load the RBF row (float2,
// coalesced), pack f16, stage in LDS; all lanes broadcast-read via
// ds_read_b128 and run v_dot2_f32_f16. Accumulate per src run in registers;
// interior nodes -> plain store, chunk-boundary nodes -> atomicAdd.
__global__ __launch_bounds__(256) void gather_stream(
    const int* __restrict__ rowptr, const int* __restrict__ srczt,
    const float* __restrict__ cC, const int* __restrict__ eidA,
    const float* __restrict__ ea, const float* __restrict__ emb,
    const float* __restrict__ dpw, const float* __restrict__ dpb,
    float* __restrict__ agg, int N, int nwaves)
{
    __shared__ unsigned int sh_ea[4][4][32];
    int lane  = threadIdx.x & 63;
    int wslot = threadIdx.x >> 6;
    int wid = __builtin_amdgcn_readfirstlane((int)((blockIdx.x * blockDim.x + threadIdx.x) >> 6));

    // per-lane weights as f16 pairs
    hf2 whA[25], whB[25];
    {
        const float* wr0 = dpw + (size_t)(2 * lane) * NRBF;
        const float* wr1 = wr0 + NRBF;
#pragma unroll
        for (int q = 0; q < 25; ++q) {
            float2 x = *(const float2*)(wr0 + 2 * q);
            float2 y = *(const float2*)(wr1 + 2 * q);
            whA[q] = pack2(x.x, x.y);
            whB[q] = pack2(y.x, y.y);
        }
    }
    float2 db = *(const float2*)(dpb + 2 * lane);

    int M  = rowptr[N];
    int CH = (M + nwaves - 1) / nwaves;
    int c0 = min(wid * CH, M);
    int c1 = min(c0 + CH, M);

    int   cur = -1, run_start = c0;
    float a0 = 0.f, a1 = 0.f;

    for (int i = c0; i < c1; i += 4) {
        int sv[4]; float cf[4]; int ed[4]; float2 ev[4]; float2 eaf[4];
        // phase 1: descriptors (uniform s_loads)
#pragma unroll
        for (int j = 0; j < 4; ++j)
            if (i + j < c1) { sv[j] = srczt[i + j]; cf[j] = cC[i + j]; ed[j] = eidA[i + j]; }
        // phase 1b: emb prefetch (L2-resident table)
#pragma unroll
        for (int j = 0; j < 4; ++j)
            if (i + j < c1) ev[j] = *(const float2*)(emb + (size_t)(sv[j] >> 20) * HIDDEN + 2 * lane);
        // phase 2: RBF row loads (coalesced 200B per edge)
#pragma unroll
        for (int j = 0; j < 4; ++j)
            if (i + j < c1 && lane < 25) eaf[j] = *(const float2*)(ea + (size_t)ed[j] * NRBF + 2 * lane);
        // phase 3: pack f16 + stage in LDS (pad words 25..27 zeroed)
#pragma unroll
        for (int j = 0; j < 4; ++j)
            if (i + j < c1 && lane < 28) {
                unsigned int u = 0u;
                if (lane < 25) {
                    hf2 p = pack2(eaf[j].x, eaf[j].y);
                    u = __builtin_bit_cast(unsigned int, p);
                }
                sh_ea[wslot][j][lane] = u;
            }
        // phase 4: compute
#pragma unroll
        for (int j = 0; j < 4; ++j) {
            if (i + j >= c1) break;
            int src = sv[j] & 0xFFFFF;
            if (src != cur) {
                if (cur >= 0) {
                    int rp0 = rowptr[cur], rp1 = rowptr[cur + 1];
                    float* dst = agg + (size_t)cur * HIDDEN + 2 * lane;
                    if (run_start == rp0 && (i + j) == rp1) {
                        *(float2*)dst = make_float2(a0, a1);
                    } else {
                        unsafeAtomicAdd(dst, a0);
                        unsafeAtomicAdd(dst + 1, a1);
                    }
                }
                cur = src; run_start = i + j; a0 = 0.f; a1 = 0.f;
            }
            float s0 = 0.f, s1 = 0.f;
#pragma unroll
            for (int q = 0; q < 6; ++q) {
                uint4 u = *(const uint4*)&sh_ea[wslot][j][q * 4];
#pragma unroll
                for (int t = 0; t < 4; ++t) {
                    unsigned int w = (t == 0) ? u.x : (t == 1) ? u.y : (t == 2) ? u.z : u.w;
                    hf2 e2 = __builtin_bit_cast(hf2, w);
                    s0 = fdot2f(e2, whA[q * 4 + t], s0);
                    s1 = fdot2f(e2, whB[q * 4 + t], s1);
                }
            }
            {
                hf2 e2 = __builtin_bit_cast(hf2, sh_ea[wslot][j][24]);
                s0 = fdot2f(e2, whA[24], s0);
                s1 = fdot2f(e2, whB[24], s1);
            }
            float W0 = (s0 + db.x) * cf[j];
            float W1 = (s1 + db.y) * cf[j];
            a0 = fmaf(W0, ev[j].x, a0);
            a1 = fmaf(W1, ev[j].y, a1);
        }
    }
    if (cur >= 0) {
        int rp0 = rowptr[cur], rp1 = rowptr[cur + 1];
        float* dst = agg + (size_t)cur * HIDDEN + 2 * lane;
        if (run_start == rp0 && c1 == rp1) {
            *(float2*)dst = make_float2(a0, a1);
        } else {
            unsafeAtomicAdd(dst, a0);
            unsafeAtomicAdd(dst + 1, a1);
        }
    }
}

// ======================= Fallback edge kernel (atomics) =======================
__global__ __launch_bounds__(256) void edge_kernel(
    const int* __restrict__ z, const int* __restrict__ ei,
    const float* __restrict__ ew, const float* __restrict__ ea,
    const float* __restrict__ emb, const float* __restrict__ dpw,
    const float* __restrict__ dpb, float* __restrict__ agg, int E)
{
    int e = blockIdx.x * 256 + threadIdx.x;
    if (e >= E) return;
    float r = ew[e];
    if (!(r < CUTOFF_F)) return;
    float C = 0.5f * (cosf(r * PI_OVER_CUTOFF) + 1.0f);
    int src = ei[e];
    int dst = ei[E + e];
    int zt  = z[dst];
    float av[NRBF];
#pragma unroll
    for (int k = 0; k < NRBF; ++k) av[k] = ea[(size_t)e * NRBF + k];
    const float* er = emb + (size_t)zt * HIDDEN;
    float*       ar = agg + (size_t)src * HIDDEN;
#pragma unroll 2
    for (int h = 0; h < HIDDEN; ++h) {
        const float* wrow = dpw + h * NRBF;
        float s0 = 0.f, s1 = 0.f;
#pragma unroll
        for (int k = 0; k < NRBF; k += 2) {
            s0 = fmaf(av[k],     wrow[k],     s0);
            s1 = fmaf(av[k + 1], wrow[k + 1], s1);
        }
        float w = (dpb[h] + s0 + s1) * C;
        unsafeAtomicAdd(&ar[h], w * er[h]);
    }
}

// ======================= Combine: tiled fp32 GEMM =======================
__global__ __launch_bounds__(256) void combine_tiled(
    const float* __restrict__ nf, const float* __restrict__ cw,
    const float* __restrict__ cb, float* out, int N)
{
    __shared__ float As[32][68];
    __shared__ float Bs[32][132];
    int tid  = threadIdx.x;
    int row0 = blockIdx.x * 64;
    int mt = (tid >> 4) << 2;
    int nt = (tid & 15) << 3;

    float acc[4][8];
    {
        float4 c0 = *(const float4*)(cb + nt);
        float4 c1 = *(const float4*)(cb + nt + 4);
#pragma unroll
        for (int mi = 0; mi < 4; ++mi) {
            acc[mi][0] = c0.x; acc[mi][1] = c0.y; acc[mi][2] = c0.z; acc[mi][3] = c0.w;
            acc[mi][4] = c1.x; acc[mi][5] = c1.y; acc[mi][6] = c1.z; acc[mi][7] = c1.w;
        }
    }

    for (int kc = 0; kc < 8; ++kc) {
        const float* src = (kc < 4) ? nf : out;
        int kbase = (kc & 3) * 32;
#pragma unroll
        for (int f = tid; f < 512; f += 256) {
            int r = f >> 3, kq = (f & 7) * 4;
            int row = row0 + r;
            float4 v = make_float4(0.f, 0.f, 0.f, 0.f);
            if (row < N) v = *(const float4*)(src + (size_t)row * HIDDEN + kbase + kq);
            As[kq + 0][r] = v.x; As[kq + 1][r] = v.y;
            As[kq + 2][r] = v.z; As[kq + 3][r] = v.w;
        }
#pragma unroll
        for (int f = tid; f < 1024; f += 256) {
            int j = f >> 3, kq = (f & 7) * 4;
            float4 v = *(const float4*)(cw + (size_t)j * 256 + kc * 32 + kq);
            Bs[kq + 0][j] = v.x; Bs[kq + 1][j] = v.y;
            Bs[kq + 2][j] = v.z; Bs[kq + 3][j] = v.w;
        }
        __syncthreads();
#pragma unroll
        for (int kk = 0; kk < 32; ++kk) {
            float4 a  = *(const float4*)&As[kk][mt];
            float4 b0 = *(const float4*)&Bs[kk][nt];
            float4 b1 = *(const float4*)&Bs[kk][nt + 4];
            const float am[4] = {a.x, a.y, a.z, a.w};
            const float bn[8] = {b0.x, b0.y, b0.z, b0.w, b1.x, b1.y, b1.z, b1.w};
#pragma unroll
            for (int mi = 0; mi < 4; ++mi)
#pragma unroll
                for (int nj = 0; nj < 8; ++nj)
                    acc[mi][nj] = fmaf(am[mi], bn[nj], acc[mi][nj]);
        }
        __syncthreads();
    }
#pragma unroll
    for (int mi = 0; mi < 4; ++mi) {
        int row = row0 + mt + mi;
        if (row < N) {
            float4* op = (float4*)(out + (size_t)row * HIDDEN + nt);
            op[0] = make_float4(acc[mi][0], acc[mi][1], acc[mi][2], acc[mi][3]);
            op[1] = make_float4(acc[mi][4], acc[mi][5], acc[mi][6], acc[mi][7]);
        }
    }
}

// ======================= launch =======================

extern "C" void kernel_launch(void* const* d_in, const int* in_sizes, int n_in,
                              void* d_out, int out_size, void* d_ws, size_t ws_size,
                              hipStream_t stream)
{
    const int*   z   = (const int*)  d_in[0];
    const float* nf  = (const float*)d_in[1];
    const int*   ei  = (const int*)  d_in[2];
    const float* ew  = (const float*)d_in[3];
    const float* ea  = (const float*)d_in[4];
    const float* emb = (const float*)d_in[5];
    const float* dpw = (const float*)d_in[6];
    const float* dpb = (const float*)d_in[7];
    const float* cw  = (const float*)d_in[8];
    const float* cb  = (const float*)d_in[9];
    float* out = (float*)d_out;

    int N = in_sizes[0];
    int E = in_sizes[3];

    size_t need = ((size_t)2 * N + 1 + 1024 + (size_t)3 * E) * 4;

    // agg accumulator lives in d_out; boundary/empty rows need zeros
    (void)hipMemsetAsync(out, 0, (size_t)N * HIDDEN * sizeof(float), stream);

    if (ws_size >= need) {
        int* rowptr  = (int*)d_ws;                 // N+1
        int* woff    = rowptr + (N + 1);           // N
        int* bsum    = woff + N;                   // 1024
        int* srcztA  = bsum + 1024;                // E
        float* cCA   = (float*)(srcztA + E);       // E
        int* eidA    = (int*)(cCA + E);            // E

        int nb1 = (N + 1023) / 1024;

        (void)hipMemsetAsync(woff, 0, (size_t)N * 4, stream);
        hist_kernel<<<(E + 255) / 256, 256, 0, stream>>>(ei, ew, woff, E);
        scan1_kernel<<<nb1, 256, 0, stream>>>(woff, rowptr, bsum, N);
        scan2_kernel<<<1, 256, 0, stream>>>(bsum, rowptr, nb1, N);
        scan3_kernel<<<nb1, 256, 0, stream>>>(rowptr, woff, bsum, N);
        scatter_kernel<<<(E + 255) / 256, 256, 0, stream>>>(z, ei, ew, woff,
                                                            srcztA, cCA, eidA, E);
        const int blocks = 2048;
        gather_stream<<<blocks, 256, 0, stream>>>(rowptr, srcztA, cCA, eidA,
                                                  ea, emb, dpw, dpb, out, N,
                                                  blocks * 4);
    } else {
        edge_kernel<<<(E + 255) / 256, 256, 0, stream>>>(z, ei, ew, ea, emb,
                                                         dpw, dpb, out, E);
    }

    combine_tiled<<<(N + 63) / 64, 256, 0, stream>>>(nf, cw, cb, out, N);
}

// Round 5
// 442.924 us; speedup vs baseline: 21.9198x; 1.1242x over previous
//
#include <hip/hip_runtime.h>

#define HIDDEN 128
#define NRBF 50
#define CUTOFF_F 5.0f
#define PI_OVER_CUTOFF 0.6283185307179586f

typedef __attribute__((ext_vector_type(2))) _Float16 hf2;
using short8_t = __attribute__((ext_vector_type(8))) short;
using f32x4_t  = __attribute__((ext_vector_type(4))) float;

#if defined(__has_builtin)
#if __has_builtin(__builtin_amdgcn_fdot2)
#define HAS_FDOT2 1
#endif
#endif

static __device__ __forceinline__ hf2 pack2(float x, float y) {
    return __builtin_bit_cast(hf2, __builtin_amdgcn_cvt_pkrtz(x, y));
}

static __device__ __forceinline__ float fdot2f(hf2 a, hf2 b, float c) {
#ifdef HAS_FDOT2
    return __builtin_amdgcn_fdot2(a, b, c, false);
#else
    return fmaf((float)a[0], (float)b[0], fmaf((float)a[1], (float)b[1], c));
#endif
}

// fp32 pair -> packed bf16x2 (RNE)
static __device__ __forceinline__ unsigned int pk_bf16(float a, float b) {
    unsigned int ua = __float_as_uint(a), ub = __float_as_uint(b);
    ua = (ua + 0x7FFFu + ((ua >> 16) & 1u)) >> 16;
    ub = (ub + 0x7FFFu + ((ub >> 16) & 1u)) >> 16;
    return ua | (ub << 16);
}

// ======================= CSR build =======================

__global__ __launch_bounds__(256) void hist_kernel(
    const int* __restrict__ ei, const float* __restrict__ ew,
    int* __restrict__ cnt, int E)
{
    int e = blockIdx.x * 256 + threadIdx.x;
    if (e >= E) return;
    float r = ew[e];
    if (r < CUTOFF_F) atomicAdd(&cnt[ei[e]], 1);
}

__global__ __launch_bounds__(256) void scan1_kernel(
    const int* __restrict__ cnt, int* __restrict__ rowptr,
    int* __restrict__ bsum, int N)
{
    __shared__ int sh[256];
    int t = threadIdx.x, b = blockIdx.x;
    int base = b * 1024 + t * 4;
    int v[4];
#pragma unroll
    for (int j = 0; j < 4; ++j) v[j] = (base + j < N) ? cnt[base + j] : 0;
    int s = v[0] + v[1] + v[2] + v[3];
    sh[t] = s;
    __syncthreads();
    for (int off = 1; off < 256; off <<= 1) {
        int x = (t >= off) ? sh[t - off] : 0;
        __syncthreads();
        sh[t] += x;
        __syncthreads();
    }
    int run = sh[t] - s;
#pragma unroll
    for (int j = 0; j < 4; ++j) {
        if (base + j < N) rowptr[base + j] = run;
        run += v[j];
    }
    if (t == 255) bsum[b] = sh[255];
}

__global__ __launch_bounds__(256) void scan2_kernel(
    int* __restrict__ bsum, int* __restrict__ rowptr, int nb, int N)
{
    __shared__ int sh[256];
    int t = threadIdx.x;
    int v = (t < nb) ? bsum[t] : 0;
    sh[t] = v;
    __syncthreads();
    for (int off = 1; off < 256; off <<= 1) {
        int x = (t >= off) ? sh[t - off] : 0;
        __syncthreads();
        sh[t] += x;
        __syncthreads();
    }
    if (t < nb) bsum[t] = sh[t] - v;
    if (t == 255) rowptr[N] = sh[255];
}

__global__ __launch_bounds__(256) void scan3_kernel(
    int* __restrict__ rowptr, int* __restrict__ woff,
    const int* __restrict__ bsum, int N)
{
    int t = threadIdx.x, b = blockIdx.x;
    int base = b * 1024 + t * 4;
    int off = bsum[b];
#pragma unroll
    for (int j = 0; j < 4; ++j) {
        int i = base + j;
        if (i < N) {
            int r = rowptr[i] + off;
            rowptr[i] = r;
            woff[i] = r;
        }
    }
}

// scatter live edges into CSR slots: int4{src|zt<<20, eid, C_bits, 0}
__global__ __launch_bounds__(256) void scatter_kernel(
    const int* __restrict__ z, const int* __restrict__ ei,
    const float* __restrict__ ew, int* __restrict__ woff,
    int4* __restrict__ slots, int E)
{
    int e = blockIdx.x * 256 + threadIdx.x;
    if (e >= E) return;
    float r = ew[e];
    if (!(r < CUTOFF_F)) return;
    float C = 0.5f * (cosf(r * PI_OVER_CUTOFF) + 1.0f);
    int src = ei[e];
    int dst = ei[E + e];
    int zt  = z[dst];
    int p = atomicAdd(&woff[src], 1);
    slots[p] = make_int4(src | (zt << 20), e, __float_as_int(C), 0);
}

// ======================= Streaming gather =======================
__global__ __launch_bounds__(256) void gather_stream(
    const int* __restrict__ rowptr, const int4* __restrict__ slots,
    const float* __restrict__ ea, const float* __restrict__ emb,
    const float* __restrict__ dpw, const float* __restrict__ dpb,
    float* __restrict__ agg, int N, int nwaves)
{
    __shared__ unsigned int sh_emb[95 * 64];       // [type][h-pair] f16x2
    __shared__ unsigned int sh_ea[4][4][32];
    int lane  = threadIdx.x & 63;
    int wslot = threadIdx.x >> 6;
    int wid = __builtin_amdgcn_readfirstlane((int)((blockIdx.x * blockDim.x + threadIdx.x) >> 6));

    // stage emb as f16 pairs in LDS
    for (int idx = threadIdx.x; idx < 95 * 64; idx += 256) {
        int row = idx >> 6, pr = idx & 63;
        float2 v = *(const float2*)(emb + (size_t)row * HIDDEN + pr * 2);
        sh_emb[idx] = __builtin_bit_cast(unsigned int, pack2(v.x, v.y));
    }

    // per-lane dp_w rows (h = 2*lane, 2*lane+1) as f16 pairs
    hf2 whA[25], whB[25];
    {
        const float* wr0 = dpw + (size_t)(2 * lane) * NRBF;
        const float* wr1 = wr0 + NRBF;
#pragma unroll
        for (int q = 0; q < 25; ++q) {
            float2 x = *(const float2*)(wr0 + 2 * q);
            float2 y = *(const float2*)(wr1 + 2 * q);
            whA[q] = pack2(x.x, x.y);
            whB[q] = pack2(y.x, y.y);
        }
    }
    float2 db = *(const float2*)(dpb + 2 * lane);
    __syncthreads();

    int M  = rowptr[N];
    int CH = (M + nwaves - 1) / nwaves;
    int c0 = min(wid * CH, M);
    int c1 = min(c0 + CH, M);

    int   cur = -1, run_start = c0;
    float a0 = 0.f, a1 = 0.f;

    for (int i = c0; i < c1; i += 4) {
        int sv[4]; float cf[4]; int ed[4]; unsigned int evu[4]; float2 eaf[4];
        // phase 1: descriptors (uniform -> s_load)
#pragma unroll
        for (int j = 0; j < 4; ++j)
            if (i + j < c1) {
                int4 sl = slots[i + j];
                sv[j] = sl.x; ed[j] = sl.y; cf[j] = __int_as_float(sl.z);
            }
        // phase 1b: emb prefetch from LDS
#pragma unroll
        for (int j = 0; j < 4; ++j)
            if (i + j < c1) evu[j] = sh_emb[(sv[j] >> 20) * 64 + lane];
        // phase 2: RBF row loads (coalesced 200B per edge)
#pragma unroll
        for (int j = 0; j < 4; ++j)
            if (i + j < c1 && lane < 25) eaf[j] = *(const float2*)(ea + (size_t)ed[j] * NRBF + 2 * lane);
        // phase 3: pack f16 + stage in LDS
#pragma unroll
        for (int j = 0; j < 4; ++j)
            if (i + j < c1 && lane < 28) {
                unsigned int u = 0u;
                if (lane < 25) u = __builtin_bit_cast(unsigned int, pack2(eaf[j].x, eaf[j].y));
                sh_ea[wslot][j][lane] = u;
            }
        // phase 4: compute
#pragma unroll
        for (int j = 0; j < 4; ++j) {
            if (i + j >= c1) break;
            int src = sv[j] & 0xFFFFF;
            if (src != cur) {
                if (cur >= 0) {
                    int rp0 = rowptr[cur], rp1 = rowptr[cur + 1];
                    float* dst = agg + (size_t)cur * HIDDEN + 2 * lane;
                    if (run_start == rp0 && (i + j) == rp1) {
                        *(float2*)dst = make_float2(a0, a1);
                    } else {
                        unsafeAtomicAdd(dst, a0);
                        unsafeAtomicAdd(dst + 1, a1);
                    }
                }
                cur = src; run_start = i + j; a0 = 0.f; a1 = 0.f;
            }
            float s0a = 0.f, s0b = 0.f, s1a = 0.f, s1b = 0.f;
#pragma unroll
            for (int q = 0; q < 6; ++q) {
                uint4 u = *(const uint4*)&sh_ea[wslot][j][q * 4];
#pragma unroll
                for (int t = 0; t < 4; ++t) {
                    unsigned int w = (t == 0) ? u.x : (t == 1) ? u.y : (t == 2) ? u.z : u.w;
                    hf2 e2 = __builtin_bit_cast(hf2, w);
                    if (t & 1) { s0b = fdot2f(e2, whA[q * 4 + t], s0b); s1b = fdot2f(e2, whB[q * 4 + t], s1b); }
                    else       { s0a = fdot2f(e2, whA[q * 4 + t], s0a); s1a = fdot2f(e2, whB[q * 4 + t], s1a); }
                }
            }
            {
                hf2 e2 = __builtin_bit_cast(hf2, sh_ea[wslot][j][24]);
                s0a = fdot2f(e2, whA[24], s0a);
                s1a = fdot2f(e2, whB[24], s1a);
            }
            float W0 = (s0a + s0b + db.x) * cf[j];
            float W1 = (s1a + s1b + db.y) * cf[j];
            hf2 eh = __builtin_bit_cast(hf2, evu[j]);
            a0 = fmaf(W0, (float)eh[0], a0);
            a1 = fmaf(W1, (float)eh[1], a1);
        }
    }
    if (cur >= 0) {
        int rp0 = rowptr[cur], rp1 = rowptr[cur + 1];
        float* dst = agg + (size_t)cur * HIDDEN + 2 * lane;
        if (run_start == rp0 && c1 == rp1) {
            *(float2*)dst = make_float2(a0, a1);
        } else {
            unsafeAtomicAdd(dst, a0);
            unsafeAtomicAdd(dst + 1, a1);
        }
    }
}

// ======================= Fallback edge kernel (atomics) =======================
__global__ __launch_bounds__(256) void edge_kernel(
    const int* __restrict__ z, const int* __restrict__ ei,
    const float* __restrict__ ew, const float* __restrict__ ea,
    const float* __restrict__ emb, const float* __restrict__ dpw,
    const float* __restrict__ dpb, float* __restrict__ agg, int E)
{
    int e = blockIdx.x * 256 + threadIdx.x;
    if (e >= E) return;
    float r = ew[e];
    if (!(r < CUTOFF_F)) return;
    float C = 0.5f * (cosf(r * PI_OVER_CUTOFF) + 1.0f);
    int src = ei[e];
    int dst = ei[E + e];
    int zt  = z[dst];
    float av[NRBF];
#pragma unroll
    for (int k = 0; k < NRBF; ++k) av[k] = ea[(size_t)e * NRBF + k];
    const float* er = emb + (size_t)zt * HIDDEN;
    float*       ar = agg + (size_t)src * HIDDEN;
#pragma unroll 2
    for (int h = 0; h < HIDDEN; ++h) {
        const float* wrow = dpw + h * NRBF;
        float s0 = 0.f, s1 = 0.f;
#pragma unroll
        for (int k = 0; k < NRBF; k += 2) {
            s0 = fmaf(av[k],     wrow[k],     s0);
            s1 = fmaf(av[k + 1], wrow[k + 1], s1);
        }
        float w = (dpb[h] + s0 + s1) * C;
        unsafeAtomicAdd(&ar[h], w * er[h]);
    }
}

// ======================= Combine: bf16 MFMA GEMM =======================
// out[n] = [nf[n] | agg[n]] @ cw.T + cb; agg lives in `out` (in-place,
// barrier-ordered: all global reads of this block's rows complete before
// stores). Block = 64 rows x 128 cols, 4 waves (16 rows each), K=256 in
// 8 steps of 32. LDS pitch 80B (20 u32) -> max 2-way bank aliasing.
__global__ __launch_bounds__(256) void combine_mfma(
    const float* __restrict__ nf, const float* __restrict__ cw,
    const float* __restrict__ cbias, float* out, int N)
{
    __shared__ unsigned int As_u[64 * 20];
    __shared__ unsigned int Bs_u[128 * 20];
    int tid  = threadIdx.x;
    int w    = tid >> 6;
    int lane = tid & 63;
    int c    = lane & 15;
    int g    = lane >> 4;
    int row0 = blockIdx.x * 64;

    f32x4_t acc[8];
#pragma unroll
    for (int q = 0; q < 8; ++q) acc[q] = (f32x4_t){0.f, 0.f, 0.f, 0.f};

    for (int ks = 0; ks < 8; ++ks) {
        const float* src = (ks < 4) ? nf : out;
        int kb = (ks & 3) * 32;
        // stage A: 64 rows x 32 k (bf16)
        {
            int r = tid >> 2, kq = tid & 3;
            int row = row0 + r;
            float4 v0 = make_float4(0.f, 0.f, 0.f, 0.f), v1 = v0;
            if (row < N) {
                const float4* p = (const float4*)(src + (size_t)row * HIDDEN + kb + kq * 8);
                v0 = p[0]; v1 = p[1];
            }
            *(uint4*)&As_u[r * 20 + kq * 4] =
                make_uint4(pk_bf16(v0.x, v0.y), pk_bf16(v0.z, v0.w),
                           pk_bf16(v1.x, v1.y), pk_bf16(v1.z, v1.w));
        }
        // stage B: 128 cols x 32 k (bf16), cw row-major [128][256]
        {
            int j = tid >> 1, hf = tid & 1;
            const float4* p = (const float4*)(cw + (size_t)j * 256 + ks * 32 + hf * 16);
            float4 b0 = p[0], b1 = p[1], b2 = p[2], b3 = p[3];
            *(uint4*)&Bs_u[j * 20 + hf * 8] =
                make_uint4(pk_bf16(b0.x, b0.y), pk_bf16(b0.z, b0.w),
                           pk_bf16(b1.x, b1.y), pk_bf16(b1.z, b1.w));
            *(uint4*)&Bs_u[j * 20 + hf * 8 + 4] =
                make_uint4(pk_bf16(b2.x, b2.y), pk_bf16(b2.z, b2.w),
                           pk_bf16(b3.x, b3.y), pk_bf16(b3.z, b3.w));
        }
        __syncthreads();
        uint4 au = *(const uint4*)&As_u[(w * 16 + c) * 20 + g * 4];
        short8_t af = __builtin_bit_cast(short8_t, au);
#pragma unroll
        for (int cbk = 0; cbk < 8; ++cbk) {
            uint4 bu = *(const uint4*)&Bs_u[(cbk * 16 + c) * 20 + g * 4];
            short8_t bf = __builtin_bit_cast(short8_t, bu);
            acc[cbk] = __builtin_amdgcn_mfma_f32_16x16x32_bf16(af, bf, acc[cbk], 0, 0, 0);
        }
        __syncthreads();
    }
    // epilogue: D row = g*4 + reg (within wave tile), col = c
#pragma unroll
    for (int cbk = 0; cbk < 8; ++cbk) {
        float bias = cbias[cbk * 16 + c];
#pragma unroll
        for (int r = 0; r < 4; ++r) {
            int row = row0 + w * 16 + g * 4 + r;
            if (row < N) out[(size_t)row * HIDDEN + cbk * 16 + c] = acc[cbk][r] + bias;
        }
    }
}

// ======================= launch =======================

extern "C" void kernel_launch(void* const* d_in, const int* in_sizes, int n_in,
                              void* d_out, int out_size, void* d_ws, size_t ws_size,
                              hipStream_t stream)
{
    const int*   z   = (const int*)  d_in[0];
    const float* nf  = (const float*)d_in[1];
    const int*   ei  = (const int*)  d_in[2];
    const float* ew  = (const float*)d_in[3];
    const float* ea  = (const float*)d_in[4];
    const float* emb = (const float*)d_in[5];
    const float* dpw = (const float*)d_in[6];
    const float* dpb = (const float*)d_in[7];
    const float* cw  = (const float*)d_in[8];
    const float* cb  = (const float*)d_in[9];
    float* out = (float*)d_out;

    int N = in_sizes[0];
    int E = in_sizes[3];

    size_t hdr = ((size_t)2 * N + 1 + 1024 + 3) & ~(size_t)3;   // u32s, 16B-align slots
    size_t need = hdr * 4 + (size_t)E * 16;

    // agg accumulator lives in d_out; boundary/empty rows need zeros
    (void)hipMemsetAsync(out, 0, (size_t)N * HIDDEN * sizeof(float), stream);

    if (ws_size >= need) {
        int*  rowptr = (int*)d_ws;                 // N+1
        int*  woff   = rowptr + (N + 1);           // N
        int*  bsum   = woff + N;                   // 1024
        int4* slots  = (int4*)((unsigned int*)d_ws + hdr);   // E slots

        int nb1 = (N + 1023) / 1024;

        (void)hipMemsetAsync(woff, 0, (size_t)N * 4, stream);
        hist_kernel<<<(E + 255) / 256, 256, 0, stream>>>(ei, ew, woff, E);
        scan1_kernel<<<nb1, 256, 0, stream>>>(woff, rowptr, bsum, N);
        scan2_kernel<<<1, 256, 0, stream>>>(bsum, rowptr, nb1, N);
        scan3_kernel<<<nb1, 256, 0, stream>>>(rowptr, woff, bsum, N);
        scatter_kernel<<<(E + 255) / 256, 256, 0, stream>>>(z, ei, ew, woff,
                                                            slots, E);
        const int blocks = 2048;
        gather_stream<<<blocks, 256, 0, stream>>>(rowptr, slots, ea, emb,
                                                  dpw, dpb, out, N, blocks * 4);
    } else {
        edge_kernel<<<(E + 255) / 256, 256, 0, stream>>>(z, ei, ew, ea, emb,
                                                         dpw, dpb, out, E);
    }

    combine_mfma<<<(N + 63) / 64, 256, 0, stream>>>(nf, cw, cb, out, N);
}